// Round 12
// baseline (1558.753 us; speedup 1.0000x reference)
//
#include <hip/hip_runtime.h>
#include <hip/hip_bf16.h>

typedef unsigned short u16;
typedef unsigned int u32;
typedef unsigned long long u64;
typedef __attribute__((ext_vector_type(8))) short s16x8;
typedef __attribute__((ext_vector_type(4))) short s16x4;
typedef __attribute__((ext_vector_type(4))) float f32x4;

__device__ inline u16 f2bf(float x) {
    u32 u = __float_as_uint(x);
    u32 r = (u + 0x7fffu + ((u >> 16) & 1u)) >> 16;
    return (u16)r;
}
__device__ inline float bf2f(u16 u) {
    return __uint_as_float(((u32)u) << 16);
}

// ---- features f32 -> bf16, with zero sentinel row at index N ----
__global__ void k_feat2bf(const float* __restrict__ f, u16* __restrict__ o,
                          int total, int nvalid) {
    int i = (blockIdx.x * 256 + threadIdx.x) * 8;
    if (i >= total) return;
    s16x8 v;
#pragma unroll
    for (int j = 0; j < 8; ++j) {
        float x = (i + j < nvalid) ? f[i + j] : 0.f;
        v[j] = (short)f2bf(x);
    }
    *(s16x8*)(o + i) = v;
}

// ---- weight swizzle: W[9][cin][128] f32 -> MFMA-B fragment-packed bf16 ----
__global__ void k_swz(const float* __restrict__ W, u16* __restrict__ o, int cin) {
    int i = blockIdx.x * 256 + threadIdx.x;
    int total = 9 * cin * 128;
    if (i >= total) return;
    int j = i & 7;
    int l = (i >> 3) & 63;
    int fr = i >> 9;
    int ct = fr & 7;
    int rest = fr >> 3;
    int kcn = cin >> 5;
    int kc = rest % kcn;
    int t = rest / kcn;
    int kk = kc * 32 + (l >> 4) * 8 + j;
    int c = ct * 16 + (l & 15);
    o[i] = f2bf(W[(t * cin + kk) * 128 + c]);
}

// ---- gather-conv: 1024 thr (16 waves x 32 voxels) x 64 output cols.
// Wave = 2 row-groups x 4 col-tiles: each B ds_read feeds 2 MFMAs; col-split
// is only 2-way (dup 2, was 4) -> halved L3 gather traffic. Weights for this
// 64-col half staged in LDS for ALL taps (144/72 KB, no loop barriers).
// A-gathers: explicit double-buffer prefetched 1 tap ahead, PINNED with
// sched_barrier(0) so the compiler cannot sink them; nbr rolled 2 ahead.
// XCD-grouped remap: the 2 half-blocks of one (vr, conv) adjacent + same mod 8.
template <int CIN>
__global__ __launch_bounds__(1024) void k_conv(
    const u16* __restrict__ srcA, const u16* __restrict__ srcB,
    const int* __restrict__ nbrA, const int* __restrict__ nbrB,
    const u16* __restrict__ wA, const u16* __restrict__ wB,
    u16* __restrict__ zoutA, u16* __restrict__ zoutB,
    float* __restrict__ statsA, float* __restrict__ statsB,
    int N) {
    constexpr int KC = CIN / 32;
    constexpr int FR = 9 * KC * 4;    // staged frags (4 col-tiles of 16)
    __shared__ u16 wl[FR * 512];
    __shared__ float sstat[128];

    // ---- block-id remap: i = c8 + 8*(2q + h); pair p = 8q + c8; half h ----
    const int nvr = (N + 511) >> 9;
    const int npairs = 2 * nvr;
    const int i = blockIdx.x;
    const int c8 = i & 7;
    const int m = i >> 3;
    const int h = m & 1;
    const int q = m >> 1;
    const int p = 8 * q + c8;
    if (p >= npairs) return;
    const int vr = p % nvr;
    const int cz = p / nvr;
    const int colset = h;

    const u16* __restrict__ src = cz ? srcB : srcA;
    const int* __restrict__ nbr = cz ? nbrB : nbrA;
    const u16* __restrict__ w = cz ? wB : wA;
    u16* __restrict__ zout = cz ? zoutB : zoutA;
    float* __restrict__ stats = cz ? statsB : statsA;

    const int tid = threadIdx.x;

    // stage this half's weights for all taps; zero stats
    for (int ii = tid; ii < FR * 64; ii += 1024) {
        int pp = ii & 63;
        int f = ii >> 6;          // (t*KC+kc)*4 + c
        int c = f & 3;
        int tk = f >> 2;
        s16x8 v = *(const s16x8*)(w + ((size_t)(tk * 8 + colset * 4 + c)) * 512 + pp * 8);
        *(s16x8*)&wl[(size_t)f * 512 + pp * 8] = v;
    }
    if (tid < 128) sstat[tid] = 0.f;
    __syncthreads();

    const int lane = tid & 63;
    const int wv = tid >> 6;          // 0..15 voxset
    const int base = vr * 512 + wv * 32;
    const int am = lane & 15;
    const int grp = lane >> 4;
    const int vi = base + (lane & 31);
    const bool vok = vi < N;

    // rolling nbr state: rc = tap t, rn = tap t+1
    int rc = vok ? nbr[vi] : N;
    int rn = vok ? nbr[N + vi] : N;

    // A double-buffer (buffer index = tap parity, constant under full unroll)
    s16x8 a[2][2][KC];
    {
        int rg0 = __shfl(rc, am);
        int rg1 = __shfl(rc, 16 + am);
        const u16* sp0 = src + (size_t)rg0 * CIN + grp * 8;
        const u16* sp1 = src + (size_t)rg1 * CIN + grp * 8;
#pragma unroll
        for (int kc = 0; kc < KC; ++kc) {
            a[0][0][kc] = *(const s16x8*)(sp0 + kc * 32);
            a[0][1][kc] = *(const s16x8*)(sp1 + kc * 32);
        }
    }

    f32x4 acc0[4], acc1[4];
#pragma unroll
    for (int c = 0; c < 4; ++c) {
        acc0[c] = (f32x4){0.f, 0.f, 0.f, 0.f};
        acc1[c] = (f32x4){0.f, 0.f, 0.f, 0.f};
    }

#pragma unroll
    for (int t = 0; t < 9; ++t) {
        const int cur = t & 1, nxt = cur ^ 1;
        // prefetch tap t+1 A-frags (unconditional; sentinel row is L1-hot)
        if (t < 8) {
            int rg0 = __shfl(rn, am);
            int rg1 = __shfl(rn, 16 + am);
            const u16* sp0 = src + (size_t)rg0 * CIN + grp * 8;
            const u16* sp1 = src + (size_t)rg1 * CIN + grp * 8;
#pragma unroll
            for (int kc = 0; kc < KC; ++kc) {
                a[nxt][0][kc] = *(const s16x8*)(sp0 + kc * 32);
                a[nxt][1][kc] = *(const s16x8*)(sp1 + kc * 32);
            }
        }
        // roll nbr 2 ahead
        int rf = N;
        if (t < 7 && vok) rf = nbr[(t + 2) * N + vi];
        // pin: the loads above may NOT sink below this point
        __builtin_amdgcn_sched_barrier(0);

        // compute tap t
        u64 mask = __ballot(rc != N);
        if (mask != 0ULL) {
            const bool e0 = (mask & 0xFFFFull) != 0;
            const bool e1 = (mask & 0xFFFF0000ull) != 0;
            const u16* lb = wl + (size_t)t * (KC * 4) * 512 + lane * 8;
#pragma unroll
            for (int kc = 0; kc < KC; ++kc) {
#pragma unroll
                for (int c = 0; c < 4; ++c) {
                    s16x8 b = *(const s16x8*)(lb + (size_t)(kc * 4 + c) * 512);
                    if (e0) acc0[c] = __builtin_amdgcn_mfma_f32_16x16x32_bf16(a[cur][0][kc], b, acc0[c], 0, 0, 0);
                    if (e1) acc1[c] = __builtin_amdgcn_mfma_f32_16x16x32_bf16(a[cur][1][kc], b, acc1[c], 0, 0, 0);
                }
            }
        }
        rc = rn;
        rn = rf;
    }

    // epilogue: lrelu, bf16 store, block-local stats (this half's 64 cols)
#pragma unroll
    for (int c = 0; c < 4; ++c) {
        float s = 0.f, qq = 0.f;
        const int col = colset * 64 + c * 16 + am;
#pragma unroll
        for (int j = 0; j < 4; ++j) {
            {
                float x = acc0[c][j];
                float z = (x > 0.f) ? x : 0.01f * x;
                int row = base + grp * 4 + j;
                if (row < N) zout[(size_t)row * 128 + col] = f2bf(z);
                s += z;
                qq += z * z;
            }
            {
                float x = acc1[c][j];
                float z = (x > 0.f) ? x : 0.01f * x;
                int row = base + 16 + grp * 4 + j;
                if (row < N) zout[(size_t)row * 128 + col] = f2bf(z);
                s += z;
                qq += z * z;
            }
        }
        s += __shfl_xor(s, 16);
        qq += __shfl_xor(qq, 16);
        s += __shfl_xor(s, 32);
        qq += __shfl_xor(qq, 32);
        if (lane < 16) {
            atomicAdd(&sstat[c * 16 + am], s);
            atomicAdd(&sstat[64 + c * 16 + am], qq);
        }
    }
    __syncthreads();
    if (tid < 64) {
        int cg = colset * 64 + tid;
        atomicAdd(stats + cg, sstat[tid]);
        atomicAdd(stats + 128 + cg, sstat[64 + tid]);
    }
}

// ---- finalize two BN stat sets -> per-channel scale/shift ----
__global__ void k_fin(const float* __restrict__ stats,
                      const float* __restrict__ g0, const float* __restrict__ b0,
                      const float* __restrict__ g1, const float* __restrict__ b1,
                      float* __restrict__ ss, int N) {
    int tid = threadIdx.x;
    int set = tid >> 7, c = tid & 127;
    const float* st = stats + set * 256;
    float invN = 1.f / (float)N;
    float m = st[c] * invN;
    float var = st[128 + c] * invN - m * m;
    const float* g = set ? g1 : g0;
    const float* b = set ? b1 : b0;
    float sc = g[c] * rsqrtf(var + 1e-5f);
    float sh = b[c] - m * sc;
    float* o = ss + set * 256;
    o[c] = sc;
    o[128 + c] = sh;
}

// ---- y = z*scale + shift (bf16 out, with zero sentinel row N) ----
__global__ void k_aff(const u16* __restrict__ z, const float* __restrict__ ss,
                      u16* __restrict__ y, int N) {
    int v = blockIdx.x * 256 + threadIdx.x;
    int total = (N + 1) * 16;
    if (v >= total) return;
    int row = v >> 4;
    int cb = (v & 15) * 8;
    s16x8 o;
    if (row < N) {
        s16x8 zi = *(const s16x8*)(z + (size_t)row * 128 + cb);
#pragma unroll
        for (int j = 0; j < 8; ++j) {
            float x = bf2f((u16)zi[j]);
            float r = x * ss[cb + j] + ss[128 + cb + j];
            o[j] = (short)f2bf(r);
        }
    } else {
        o = (s16x8){0, 0, 0, 0, 0, 0, 0, 0};
    }
    *(s16x8*)(y + (size_t)row * 128 + cb) = o;
}

// ---- out = bn(z3) + bn(z4), f32 ----
__global__ void k_final(const u16* __restrict__ z3, const u16* __restrict__ z4,
                        const float* __restrict__ ssA, const float* __restrict__ ssB,
                        float* __restrict__ out, int N) {
    int v = blockIdx.x * 256 + threadIdx.x;
    int total = N * 32;
    if (v >= total) return;
    int row = v >> 5;
    int cb = (v & 31) * 4;
    s16x4 a = *(const s16x4*)(z3 + (size_t)row * 128 + cb);
    s16x4 b = *(const s16x4*)(z4 + (size_t)row * 128 + cb);
    f32x4 o;
#pragma unroll
    for (int j = 0; j < 4; ++j) {
        int c = cb + j;
        o[j] = bf2f((u16)a[j]) * ssA[c] + ssA[128 + c] +
               bf2f((u16)b[j]) * ssB[c] + ssB[128 + c];
    }
    *(f32x4*)(out + (size_t)row * 128 + cb) = o;
}

extern "C" void kernel_launch(void* const* d_in, const int* in_sizes, int n_in,
                              void* d_out, int out_size, void* d_ws, size_t ws_size,
                              hipStream_t stream) {
    const float* feat = (const float*)d_in[0];
    const int* nbr31 = (const int*)d_in[1];
    const int* nbr13 = (const int*)d_in[2];
    const float* W1 = (const float*)d_in[3];
    const float* W12 = (const float*)d_in[4];
    const float* W2 = (const float*)d_in[5];
    const float* W3 = (const float*)d_in[6];
    const float* g0 = (const float*)d_in[7];
    const float* b0 = (const float*)d_in[8];
    const float* g02 = (const float*)d_in[9];
    const float* b02 = (const float*)d_in[10];
    const float* g1 = (const float*)d_in[11];
    const float* b1 = (const float*)d_in[12];
    const float* g2 = (const float*)d_in[13];
    const float* b2 = (const float*)d_in[14];
    float* out = (float*)d_out;
    const int N = in_sizes[0] / 64;  // 200000

    char* p = (char*)d_ws;
    auto alloc = [&](size_t bytes) {
        char* r = p;
        p += (bytes + 255) & ~(size_t)255;
        return r;
    };
    float* stats = (float*)alloc(4 * 256 * sizeof(float));
    float* ss = (float*)alloc(4 * 256 * sizeof(float));
    u16* featbf = (u16*)alloc((size_t)(N + 1) * 64 * 2);
    u16* w1 = (u16*)alloc((size_t)9 * 64 * 128 * 2);
    u16* w2 = (u16*)alloc((size_t)9 * 64 * 128 * 2);
    u16* w12 = (u16*)alloc((size_t)9 * 128 * 128 * 2);
    u16* w3 = (u16*)alloc((size_t)9 * 128 * 128 * 2);
    u16* zA = (u16*)alloc((size_t)N * 128 * 2);
    u16* zB = (u16*)alloc((size_t)N * 128 * 2);
    u16* y1 = (u16*)alloc((size_t)(N + 1) * 128 * 2);
    u16* y2 = (u16*)alloc((size_t)(N + 1) * 128 * 2);

    hipMemsetAsync(stats, 0, 4 * 256 * sizeof(float), stream);

    int totF = (N + 1) * 64;
    k_feat2bf<<<(totF / 8 + 255) / 256, 256, 0, stream>>>(feat, featbf, totF, N * 64);
    k_swz<<<(9 * 64 * 128 + 255) / 256, 256, 0, stream>>>(W1, w1, 64);
    k_swz<<<(9 * 64 * 128 + 255) / 256, 256, 0, stream>>>(W2, w2, 64);
    k_swz<<<(9 * 128 * 128 + 255) / 256, 256, 0, stream>>>(W12, w12, 128);
    k_swz<<<(9 * 128 * 128 + 255) / 256, 256, 0, stream>>>(W3, w3, 128);

    // flat grid with XCD-grouping remap: 8 * 2 * ceil(npairs/8) blocks
    int nvr = (N + 511) / 512;
    int npairs = 2 * nvr;
    int nblk = 8 * 2 * ((npairs + 7) / 8);

    // stage 1: cz=0: conv(nbr31, W1) -> zA/stats0 ; cz=1: conv(nbr13, W2) -> zB/stats1
    k_conv<64><<<nblk, 1024, 0, stream>>>(
        featbf, featbf, nbr31, nbr13, w1, w2, zA, zB, stats + 0, stats + 256, N);
    k_fin<<<1, 256, 0, stream>>>(stats, g0, b0, g1, b1, ss, N);
    int ablk = ((N + 1) * 16 + 255) / 256;
    k_aff<<<ablk, 256, 0, stream>>>(zA, ss + 0, y1, N);
    k_aff<<<ablk, 256, 0, stream>>>(zB, ss + 256, y2, N);
    // stage 2: cz=0: conv(y1, nbr13, W12) -> zA ; cz=1: conv(y2, nbr31, W3) -> zB
    k_conv<128><<<nblk, 1024, 0, stream>>>(
        y1, y2, nbr13, nbr31, w12, w3, zA, zB, stats + 512, stats + 768, N);
    k_fin<<<1, 256, 0, stream>>>(stats + 512, g02, b02, g2, b2, ss + 512, N);
    k_final<<<(N * 32 + 255) / 256, 256, 0, stream>>>(zA, zB, ss + 512, ss + 768, out, N);
}